// Round 2
// baseline (4168.991 us; speedup 1.0000x reference)
//
#include <hip/hip_runtime.h>
#include <math.h>

#define NBATCH 4
#define LSEQ 8192
#define TLOC 4608          // local timeline length
#define TBASE 3584         // absolute time of local t=0
#define NLAYER 40
#define CS (NBATCH*TLOC)   // channel stride in X buffers
#define SKIP_T0 4096       // local start of skip window (abs 7680)
#define SKIP_LEN 512
#define NCLS 256

// ws layout (floats):
//  X0      at 0        size 128*4*4608 = 2359296
//  X1      at 2359296  size 2359296
//  skip    at 4718592  size 512*4*512  = 1048576
//  AT      at 5767168  size 40*256*256 = 2621440   (dilated_w transposed [i][kk][co])
//  ET      at 8388608  size 512*256    = 131072    (end_w transposed [sc][cl])
// total 8519680 floats = 34,078,720 bytes

// ---- prep: AT[i][kk][co] = Wd[i][co][ci][kt],  kk = kt*128 + ci ----
__global__ __launch_bounds__(256) void k_prep_a(const float* __restrict__ Wd,
                                                float* __restrict__ AT) {
    __shared__ float tile[32][257];
    int bi = blockIdx.x;
    int i = bi >> 3;            // layer
    int co0 = (bi & 7) * 32;    // co block
    int tid = threadIdx.x;
    // read coalesced: 32 co rows x 256 (ci*2+kt)
    #pragma unroll
    for (int e = 0; e < 32; e++) {
        int idx = e * 256 + tid;
        int co_l = idx >> 8;
        int rem = idx & 255;
        tile[co_l][rem] = Wd[(i * 256 + co0 + co_l) * 256 + rem];
    }
    __syncthreads();
    // write coalesced over co
    #pragma unroll
    for (int e = 0; e < 32; e++) {
        int idx = e * 256 + tid;
        int kk = idx >> 5;
        int co_l = idx & 31;
        int rem = ((kk & 127) << 1) | (kk >> 7);
        AT[(i * 256 + kk) * 256 + co0 + co_l] = tile[co_l][rem];
    }
}

// ---- prep: ET[sc][cl] = Ew[cl][sc] ----
__global__ __launch_bounds__(256) void k_prep_e(const float* __restrict__ Ew,
                                                float* __restrict__ ET) {
    int idx = blockIdx.x * 256 + threadIdx.x;   // over 512*256
    int cl = idx & 255;
    int sc = idx >> 8;
    ET[sc * 256 + cl] = Ew[cl * 512 + sc];
}

// ---- start conv (1x1): X0[c][n][t] = start_w[c] * input[n][TBASE+t] ----
__global__ __launch_bounds__(256) void k_start(const float* __restrict__ input,
                                               const float* __restrict__ start_w,
                                               float* __restrict__ X) {
    int idx = blockIdx.x * 256 + threadIdx.x;   // over 128*4*4608
    int t = idx % TLOC;
    int rest = idx / TLOC;
    int n = rest & 3;
    int c = rest >> 2;
    X[idx] = start_w[c] * input[n * LSEQ + TBASE + t];
}

// ---- one WaveNet layer: dilated conv + gate + residual + skip ----
__global__ __launch_bounds__(512) void k_layer(const float* __restrict__ Xin,
                                               float* __restrict__ Xout,
                                               float* __restrict__ skipbuf,
                                               const float* __restrict__ AT,  // [256 kk][256 co]
                                               const float* __restrict__ Wr,  // [128][128]
                                               const float* __restrict__ Ws,  // [512][128]
                                               int d) {
    __shared__ float As[8][256];
    __shared__ float Bs[8][64];
    __shared__ float Zs[128][65];

    const int tid = threadIdx.x;
    const int tm = tid >> 4;    // 0..31 -> channel group (4 ch per half)
    const int tn = tid & 15;    // 0..15 -> position group (4 pos)
    const int t0 = blockIdx.x * 64;
    const int n = blockIdx.y;

    const float* Xn = Xin + n * TLOC;

    float acc[8][4];
    #pragma unroll
    for (int j = 0; j < 8; j++)
        #pragma unroll
        for (int p = 0; p < 4; p++) acc[j][p] = 0.f;

    // h = A(256x256) * B(256x64);  kk = kt*128+ci, B[kk][tt] = x[ci][t0+tt - (kt?0:d)]
    for (int kc = 0; kc < 256; kc += 8) {
        #pragma unroll
        for (int e = 0; e < 4; e++) {
            int idx = e * 512 + tid;
            int k = idx >> 8, co = idx & 255;
            As[k][co] = AT[(kc + k) * 256 + co];
        }
        {
            int k = tid >> 6, tt = tid & 63;
            int kk = kc + k;
            int ci = kk & 127;
            int t = t0 + tt - ((kk >> 7) ? 0 : d);
            if (t < 0) t = 0;                     // garbage-safe region
            Bs[k][tt] = Xn[ci * CS + t];
        }
        __syncthreads();
        #pragma unroll
        for (int k = 0; k < 8; k++) {
            float a[8], b[4];
            #pragma unroll
            for (int j = 0; j < 4; j++) a[j] = As[k][tm * 4 + j];
            #pragma unroll
            for (int j = 0; j < 4; j++) a[4 + j] = As[k][128 + tm * 4 + j];
            #pragma unroll
            for (int p = 0; p < 4; p++) b[p] = Bs[k][tn * 4 + p];
            #pragma unroll
            for (int j = 0; j < 8; j++)
                #pragma unroll
                for (int p = 0; p < 4; p++) acc[j][p] = fmaf(a[j], b[p], acc[j][p]);
        }
        __syncthreads();
    }

    // gate: z = tanh(h[0:128]) * sigmoid(h[128:256])
    #pragma unroll
    for (int j = 0; j < 4; j++)
        #pragma unroll
        for (int p = 0; p < 4; p++) {
            float hz = acc[j][p];
            float hg = acc[4 + j][p];
            float z = tanhf(hz) * (1.0f / (1.0f + expf(-hg)));
            Zs[tm * 4 + j][tn * 4 + p] = z;
        }
    __syncthreads();

    // residual: Xout = Wr(128x128) * z + Xin
    {
        float racc[4][4];
        #pragma unroll
        for (int j = 0; j < 4; j++)
            #pragma unroll
            for (int p = 0; p < 4; p++) racc[j][p] = 0.f;
        #pragma unroll 4
        for (int dc = 0; dc < 128; dc++) {
            float b[4];
            #pragma unroll
            for (int p = 0; p < 4; p++) b[p] = Zs[dc][tn * 4 + p];
            #pragma unroll
            for (int j = 0; j < 4; j++) {
                float w = Wr[(tm * 4 + j) * 128 + dc];
                #pragma unroll
                for (int p = 0; p < 4; p++) racc[j][p] = fmaf(w, b[p], racc[j][p]);
            }
        }
        #pragma unroll
        for (int j = 0; j < 4; j++) {
            int rc = tm * 4 + j;
            #pragma unroll
            for (int p = 0; p < 4; p++) {
                int t = t0 + tn * 4 + p;
                Xout[rc * CS + n * TLOC + t] = racc[j][p] + Xn[rc * CS + t];
            }
        }
    }

    // skip: only for tiles inside the output window
    if (t0 >= SKIP_T0) {
        int tsbase = t0 - SKIP_T0 + tn * 4;
        for (int pass = 0; pass < 4; pass++) {
            float sacc[4][4];
            #pragma unroll
            for (int j = 0; j < 4; j++)
                #pragma unroll
                for (int p = 0; p < 4; p++) sacc[j][p] = 0.f;
            #pragma unroll 4
            for (int dc = 0; dc < 128; dc++) {
                float b[4];
                #pragma unroll
                for (int p = 0; p < 4; p++) b[p] = Zs[dc][tn * 4 + p];
                #pragma unroll
                for (int j = 0; j < 4; j++) {
                    float w = Ws[(pass * 128 + tm * 4 + j) * 128 + dc];
                    #pragma unroll
                    for (int p = 0; p < 4; p++) sacc[j][p] = fmaf(w, b[p], sacc[j][p]);
                }
            }
            #pragma unroll
            for (int j = 0; j < 4; j++) {
                int sc = pass * 128 + tm * 4 + j;
                #pragma unroll
                for (int p = 0; p < 4; p++) {
                    int o = sc * (NBATCH * SKIP_LEN) + n * SKIP_LEN + tsbase + p;
                    skipbuf[o] += sacc[j][p];
                }
            }
        }
    }
}

// ---- end: out[(n*512+t)*256+cl] = sum_sc ET[sc][cl]*relu(skip[sc][n][t]) + Eb[cl] ----
__global__ __launch_bounds__(256) void k_end(const float* __restrict__ skipbuf,
                                             const float* __restrict__ ET,
                                             const float* __restrict__ Eb,
                                             float* __restrict__ out) {
    __shared__ float ss[512][16];
    int n = blockIdx.x >> 5;
    int tt0 = (blockIdx.x & 31) * 16;
    int tid = threadIdx.x;
    #pragma unroll
    for (int e = 0; e < 32; e++) {
        int idx = e * 256 + tid;
        int sc = idx >> 4, tt = idx & 15;
        float v = skipbuf[sc * (NBATCH * SKIP_LEN) + n * SKIP_LEN + tt0 + tt];
        ss[sc][tt] = fmaxf(v, 0.f);
    }
    __syncthreads();
    float accv[16];
    float bias = Eb[tid];
    #pragma unroll
    for (int i = 0; i < 16; i++) accv[i] = bias;
    #pragma unroll 4
    for (int sc = 0; sc < 512; sc++) {
        float w = ET[sc * 256 + tid];
        #pragma unroll
        for (int i = 0; i < 16; i++) accv[i] = fmaf(w, ss[sc][i], accv[i]);
    }
    #pragma unroll
    for (int i = 0; i < 16; i++) {
        int t = tt0 + i;
        out[(n * SKIP_LEN + t) * NCLS + tid] = accv[i];
    }
}

extern "C" void kernel_launch(void* const* d_in, const int* in_sizes, int n_in,
                              void* d_out, int out_size, void* d_ws, size_t ws_size,
                              hipStream_t stream) {
    const float* input      = (const float*)d_in[0];
    const float* start_w    = (const float*)d_in[1];
    const float* dilated_w  = (const float*)d_in[2];
    const float* residual_w = (const float*)d_in[3];
    const float* skip_w     = (const float*)d_in[4];
    const float* end_w      = (const float*)d_in[5];
    const float* end_b      = (const float*)d_in[6];
    float* out = (float*)d_out;
    float* ws = (float*)d_ws;

    float* X0      = ws;
    float* X1      = ws + 2359296;
    float* skipbuf = ws + 4718592;
    float* AT      = ws + 5767168;
    float* ET      = ws + 8388608;

    hipMemsetAsync(skipbuf, 0, (size_t)1048576 * sizeof(float), stream);
    k_prep_a<<<dim3(320), 256, 0, stream>>>(dilated_w, AT);
    k_prep_e<<<dim3(512), 256, 0, stream>>>(end_w, ET);
    k_start<<<dim3(9216), 256, 0, stream>>>(input, start_w, X0);

    for (int i = 0; i < NLAYER; i++) {
        int d = 1 << (i % 10);
        const float* Xi = (i & 1) ? X1 : X0;
        float* Xo = (i & 1) ? X0 : X1;
        k_layer<<<dim3(72, 4), 512, 0, stream>>>(
            Xi, Xo, skipbuf,
            AT + (size_t)i * 65536,
            residual_w + (size_t)i * 16384,
            skip_w + (size_t)i * 65536,
            d);
    }
    k_end<<<dim3(128), 256, 0, stream>>>(skipbuf, ET, end_b, out);
}

// Round 4
// 1654.589 us; speedup vs baseline: 2.5197x; 2.5197x over previous
//
#include <hip/hip_runtime.h>
#include <stdint.h>

#define NB 4
#define LSEQ 8192
#define TLOC 4608
#define TBASE 3584
#define NLAYER 40
#define SKIP_T0 4096
#define SKIP_LEN 512
#define NCLS 256

typedef float f32x4 __attribute__((ext_vector_type(4)));
typedef short bf16x8 __attribute__((ext_vector_type(8)));   // 8 bf16 in 4 VGPRs

typedef const __attribute__((address_space(1))) uint32_t GU32;
typedef __attribute__((address_space(3))) uint32_t LU32;

__device__ __forceinline__ void gload16(const void* g, void* l) {
    __builtin_amdgcn_global_load_lds((GU32*)g, (LU32*)l, 16, 0, 0);
}

__device__ __forceinline__ uint16_t f2bf(float x) {
    uint32_t u = __builtin_bit_cast(uint32_t, x);
    uint32_t r = (u + 0x7FFFu + ((u >> 16) & 1u)) >> 16;   // RNE
    return (uint16_t)r;
}
__device__ __forceinline__ float bf2f(uint16_t h) {
    uint32_t u = ((uint32_t)h) << 16;
    return __builtin_bit_cast(float, u);
}
__device__ __forceinline__ uint2 pack4(const uint16_t a[4]) {
    return make_uint2((uint32_t)a[0] | ((uint32_t)a[1] << 16),
                      (uint32_t)a[2] | ((uint32_t)a[3] << 16));
}

// ---------------- prep: dilated weights -> pre-swizzled split-bf16 global image ----------
// image per layer: 8 chunks x [co 256][kkc 32] u16, in-row u16 index = kkc ^ (((co>>1)&3)<<3)
// value at (co, kk=ch*32+kkc) = Wd[i][co][ci][kt], kk = kt*128+ci
__global__ __launch_bounds__(256) void k_prep_a(const float* __restrict__ Wd,
                                                uint16_t* __restrict__ AgH,
                                                uint16_t* __restrict__ AgL) {
    __shared__ float tile[32][257];
    int bi = blockIdx.x;
    int i = bi >> 3;
    int co0 = (bi & 7) * 32;
    int tid = threadIdx.x;
    #pragma unroll
    for (int e = 0; e < 32; ++e) {
        int idx = e * 256 + tid;
        int co_l = idx >> 8, rem = idx & 255;
        tile[co_l][rem] = Wd[(size_t)(i * 256 + co0 + co_l) * 256 + rem];
    }
    __syncthreads();
    #pragma unroll
    for (int e = 0; e < 32; ++e) {
        int co_l = e;
        int kk = tid;
        int ci = kk & 127, kt = kk >> 7;
        float v = tile[co_l][ci * 2 + kt];
        uint16_t h = f2bf(v);
        uint16_t lo = f2bf(v - bf2f(h));
        int co = co0 + co_l;
        int ch = kk >> 5, kkc = kk & 31;
        size_t o = ((size_t)(i * 8 + ch) * 256 + co) * 32 + (kkc ^ (((co >> 1) & 3) << 3));
        AgH[o] = h;
        AgL[o] = lo;
    }
}

// ---------------- prep: residual & skip weights -> straight split bf16 ----------
__global__ __launch_bounds__(256) void k_prep_w(const float* __restrict__ Wr, const float* __restrict__ Ws,
                                                uint16_t* __restrict__ WrH, uint16_t* __restrict__ WrL,
                                                uint16_t* __restrict__ WsH, uint16_t* __restrict__ WsL) {
    int idx = blockIdx.x * 256 + threadIdx.x;
    const int NR = NLAYER * 16384;
    if (idx < NR) {
        float v = Wr[idx];
        uint16_t h = f2bf(v);
        WrH[idx] = h; WrL[idx] = f2bf(v - bf2f(h));
    } else {
        int j = idx - NR;
        float v = Ws[j];
        uint16_t h = f2bf(v);
        WsH[j] = h; WsL[j] = f2bf(v - bf2f(h));
    }
}

// ---------------- prep: ET[sc][cl] = Ew[cl][sc] ----------
__global__ __launch_bounds__(256) void k_prep_e(const float* __restrict__ Ew,
                                                float* __restrict__ ET) {
    int idx = blockIdx.x * 256 + threadIdx.x;
    int cl = idx & 255;
    int sc = idx >> 8;
    ET[sc * 256 + cl] = Ew[cl * 512 + sc];
}

// ---------------- start conv: X[n][t][c] = sw[c]*input, split hi/lo ----------
__global__ __launch_bounds__(256) void k_start(const float* __restrict__ input,
                                               const float* __restrict__ sw,
                                               uint16_t* __restrict__ Xh, uint16_t* __restrict__ Xl) {
    int n = blockIdx.y;
    int inner = blockIdx.x * 256 + threadIdx.x;     // over 4608*128
    int t = inner >> 7, c = inner & 127;
    float x = sw[c] * input[n * LSEQ + TBASE + t];
    uint16_t h = f2bf(x);
    size_t o = (size_t)(n * TLOC + t) * 128 + c;
    Xh[o] = h;
    Xl[o] = f2bf(x - bf2f(h));
}

// ---------------- one WaveNet layer: MFMA dilated conv + gate + residual + fused skip ----------
__global__ __launch_bounds__(256, 2) void k_layer(
    const uint16_t* __restrict__ XhIn, const uint16_t* __restrict__ XlIn,
    uint16_t* __restrict__ XhOut, uint16_t* __restrict__ XlOut,
    float* __restrict__ skipbuf,
    const uint16_t* __restrict__ AgH, const uint16_t* __restrict__ AgL,  // layer slab, pre-swizzled
    const uint16_t* __restrict__ WrH, const uint16_t* __restrict__ WrL,  // [128][128]
    const uint16_t* __restrict__ WsH, const uint16_t* __restrict__ WsL,  // [512][128]
    int d)
{
    __shared__ uint16_t AsH[8192];   // [co 256][kkc 32] swizzled (16 KB)
    __shared__ uint16_t AsL[8192];
    __shared__ uint16_t BsH[1024];   // [tt 32][ci 32] swizzled (2 KB)
    __shared__ uint16_t BsL[1024];
    __shared__ uint16_t ZtH[4096];   // [tt 32][dc 128] swizzled (8 KB)
    __shared__ uint16_t ZtL[4096];

    const int tid = threadIdx.x;
    const int w  = tid >> 6;
    const int l  = tid & 63;
    const int g  = l >> 4;
    const int lq = l & 15;
    const int t0 = blockIdx.x * 32;
    const int nb = blockIdx.y;

    f32x4 acc[2][2][2];   // [pm][mi][ni]
    #pragma unroll
    for (int pm = 0; pm < 2; ++pm)
        #pragma unroll
        for (int mi = 0; mi < 2; ++mi)
            #pragma unroll
            for (int ni = 0; ni < 2; ++ni)
                acc[pm][mi][ni] = (f32x4){0.f, 0.f, 0.f, 0.f};

    // ---- main GEMM: h[co 256][tt 32] = sum_kk A[kk][co] * B[kk][tt], K = 256 in 8 chunks ----
    for (int ch = 0; ch < 8; ++ch) {
        // stage A chunk (pre-swizzled image, linear DMA copy)
        #pragma unroll
        for (int j = 0; j < 4; ++j) {
            gload16(AgH + (size_t)ch * 8192 + (j * 256 + tid) * 8, AsH + (j * 256 + tid) * 8);
            gload16(AgL + (size_t)ch * 8192 + (j * 256 + tid) * 8, AsL + (j * 256 + tid) * 8);
        }
        // stage B chunk: waves 0,1 -> BsH, waves 2,3 -> BsL (inverse-swizzled global src, linear dst)
        {
            const int s = tid & 127;                 // 16B slot
            const int b = s * 16;                    // image byte
            const int tt = b >> 6;
            const int e = (b & 63) ^ (((tt >> 1) & 3) << 4);
            const int ci = ((ch & 3) << 5) + (e >> 1);
            int t = t0 + tt - ((ch < 4) ? d : 0);
            if (t < 0) t = 0;                        // garbage-safe region
            const size_t gi = (size_t)(nb * TLOC + t) * 128 + ci;
            if (tid < 128)
                gload16(XhIn + gi, BsH + s * 8);
            else
                gload16(XlIn + gi, BsL + s * 8);
        }
        __syncthreads();

        bf16x8 Bh[2], Bl[2];
        #pragma unroll
        for (int ni = 0; ni < 2; ++ni) {
            int tt = ni * 16 + lq;
            int byte = (tt * 64 + g * 16) ^ (((tt >> 1) & 3) << 4);
            Bh[ni] = *(const bf16x8*)((const char*)BsH + byte);
            Bl[ni] = *(const bf16x8*)((const char*)BsL + byte);
        }
        bf16x8 Ah[2][2], Al[2][2];
        #pragma unroll
        for (int pm = 0; pm < 2; ++pm)
            #pragma unroll
            for (int mi = 0; mi < 2; ++mi) {
                int co = pm * 128 + w * 32 + mi * 16 + lq;
                int byte = (co * 64 + g * 16) ^ (((co >> 1) & 3) << 4);
                Ah[pm][mi] = *(const bf16x8*)((const char*)AsH + byte);
                Al[pm][mi] = *(const bf16x8*)((const char*)AsL + byte);
            }
        #pragma unroll
        for (int pm = 0; pm < 2; ++pm)
            #pragma unroll
            for (int mi = 0; mi < 2; ++mi)
                #pragma unroll
                for (int ni = 0; ni < 2; ++ni) {
                    f32x4 c = acc[pm][mi][ni];
                    c = __builtin_amdgcn_mfma_f32_16x16x32_bf16(Ah[pm][mi], Bh[ni], c, 0, 0, 0);
                    c = __builtin_amdgcn_mfma_f32_16x16x32_bf16(Ah[pm][mi], Bl[ni], c, 0, 0, 0);
                    c = __builtin_amdgcn_mfma_f32_16x16x32_bf16(Al[pm][mi], Bh[ni], c, 0, 0, 0);
                    acc[pm][mi][ni] = c;
                }
        __syncthreads();
    }

    // ---- gate (intra-thread pairing co / co+128) + write z to LDS split hi/lo ----
    #pragma unroll
    for (int mi = 0; mi < 2; ++mi)
        #pragma unroll
        for (int ni = 0; ni < 2; ++ni) {
            uint16_t zh[4], zl[4];
            #pragma unroll
            for (int r = 0; r < 4; ++r) {
                float h1 = acc[0][mi][ni][r];
                float h2 = acc[1][mi][ni][r];
                float e1 = __builtin_amdgcn_exp2f(h1 * -2.885390082f);   // e^{-2 h1}
                float th = 2.0f * __builtin_amdgcn_rcpf(1.0f + e1) - 1.0f;
                float e2 = __builtin_amdgcn_exp2f(h2 * -1.442695041f);   // e^{-h2}
                float sg = __builtin_amdgcn_rcpf(1.0f + e2);
                float z = th * sg;
                zh[r] = f2bf(z);
                zl[r] = f2bf(z - bf2f(zh[r]));
            }
            int tt = ni * 16 + lq;
            int dc0 = w * 32 + mi * 16 + g * 4;
            int idx = tt * 128 + (dc0 ^ ((tt & 7) << 3));
            *(uint2*)(ZtH + idx) = pack4(zh);
            *(uint2*)(ZtL + idx) = pack4(zl);
        }
    __syncthreads();

    // ---- residual GEMM: r[rc 128][tt 32] = Wr * z, K = 128 ----
    f32x4 racc[2][2];
    #pragma unroll
    for (int mi = 0; mi < 2; ++mi)
        #pragma unroll
        for (int ni = 0; ni < 2; ++ni)
            racc[mi][ni] = (f32x4){0.f, 0.f, 0.f, 0.f};
    #pragma unroll
    for (int ch4 = 0; ch4 < 4; ++ch4) {
        int dc0 = ch4 * 32 + g * 8;
        bf16x8 bh[2], bl[2];
        #pragma unroll
        for (int ni = 0; ni < 2; ++ni) {
            int tt = ni * 16 + lq;
            int idx = tt * 128 + (dc0 ^ ((tt & 7) << 3));
            bh[ni] = *(const bf16x8*)(ZtH + idx);
            bl[ni] = *(const bf16x8*)(ZtL + idx);
        }
        #pragma unroll
        for (int mi = 0; mi < 2; ++mi) {
            int rc = w * 32 + mi * 16 + lq;
            bf16x8 ah = *(const bf16x8*)(WrH + rc * 128 + dc0);
            bf16x8 al = *(const bf16x8*)(WrL + rc * 128 + dc0);
            #pragma unroll
            for (int ni = 0; ni < 2; ++ni) {
                f32x4 c = racc[mi][ni];
                c = __builtin_amdgcn_mfma_f32_16x16x32_bf16(ah, bh[ni], c, 0, 0, 0);
                c = __builtin_amdgcn_mfma_f32_16x16x32_bf16(ah, bl[ni], c, 0, 0, 0);
                c = __builtin_amdgcn_mfma_f32_16x16x32_bf16(al, bh[ni], c, 0, 0, 0);
                racc[mi][ni] = c;
            }
        }
    }
    // residual epilogue: Xout = racc + Xin (b64 hi/lo I/O)
    #pragma unroll
    for (int mi = 0; mi < 2; ++mi)
        #pragma unroll
        for (int ni = 0; ni < 2; ++ni) {
            int tt = ni * 16 + lq;
            int c0 = w * 32 + mi * 16 + g * 4;
            size_t gi = (size_t)(nb * TLOC + t0 + tt) * 128 + c0;
            uint2 xh = *(const uint2*)(XhIn + gi);
            uint2 xl = *(const uint2*)(XlIn + gi);
            uint16_t oh[4], ol[4];
            #pragma unroll
            for (int r = 0; r < 4; ++r) {
                uint16_t hh = (uint16_t)(((r < 2 ? xh.x : xh.y) >> ((r & 1) * 16)) & 0xFFFF);
                uint16_t ll = (uint16_t)(((r < 2 ? xl.x : xl.y) >> ((r & 1) * 16)) & 0xFFFF);
                float x = bf2f(hh) + bf2f(ll) + racc[mi][ni][r];
                oh[r] = f2bf(x);
                ol[r] = f2bf(x - bf2f(oh[r]));
            }
            *(uint2*)(XhOut + gi) = pack4(oh);
            *(uint2*)(XlOut + gi) = pack4(ol);
        }

    // ---- fused skip conv for output-window tiles: skip[sc 512][tt 32] += Ws * z ----
    if (t0 >= SKIP_T0) {
        #pragma unroll
        for (int hf = 0; hf < 2; ++hf) {
            f32x4 sacc[4][2];
            #pragma unroll
            for (int mi = 0; mi < 4; ++mi)
                #pragma unroll
                for (int ni = 0; ni < 2; ++ni)
                    sacc[mi][ni] = (f32x4){0.f, 0.f, 0.f, 0.f};
            #pragma unroll
            for (int ch4 = 0; ch4 < 4; ++ch4) {
                int dc0 = ch4 * 32 + g * 8;
                bf16x8 bh[2], bl[2];
                #pragma unroll
                for (int ni = 0; ni < 2; ++ni) {
                    int tt = ni * 16 + lq;
                    int idx = tt * 128 + (dc0 ^ ((tt & 7) << 3));
                    bh[ni] = *(const bf16x8*)(ZtH + idx);
                    bl[ni] = *(const bf16x8*)(ZtL + idx);
                }
                #pragma unroll
                for (int mi = 0; mi < 4; ++mi) {
                    int sc = hf * 256 + w * 64 + mi * 16 + lq;
                    bf16x8 ah = *(const bf16x8*)(WsH + sc * 128 + dc0);
                    bf16x8 al = *(const bf16x8*)(WsL + sc * 128 + dc0);
                    #pragma unroll
                    for (int ni = 0; ni < 2; ++ni) {
                        f32x4 c = sacc[mi][ni];
                        c = __builtin_amdgcn_mfma_f32_16x16x32_bf16(ah, bh[ni], c, 0, 0, 0);
                        c = __builtin_amdgcn_mfma_f32_16x16x32_bf16(ah, bl[ni], c, 0, 0, 0);
                        c = __builtin_amdgcn_mfma_f32_16x16x32_bf16(al, bh[ni], c, 0, 0, 0);
                        sacc[mi][ni] = c;
                    }
                }
            }
            #pragma unroll
            for (int mi = 0; mi < 4; ++mi)
                #pragma unroll
                for (int ni = 0; ni < 2; ++ni)
                    #pragma unroll
                    for (int r = 0; r < 4; ++r) {
                        int sc = hf * 256 + w * 64 + mi * 16 + g * 4 + r;
                        int ts = t0 - SKIP_T0 + ni * 16 + lq;
                        skipbuf[sc * (NB * SKIP_LEN) + nb * SKIP_LEN + ts] += sacc[mi][ni][r];
                    }
        }
    }
}

// ---------------- end conv (f32 VALU, small) ----------
__global__ __launch_bounds__(256) void k_end(const float* __restrict__ skipbuf,
                                             const float* __restrict__ ET,
                                             const float* __restrict__ Eb,
                                             float* __restrict__ out) {
    __shared__ float ss[512][16];
    int n = blockIdx.x >> 5;
    int tt0 = (blockIdx.x & 31) * 16;
    int tid = threadIdx.x;
    #pragma unroll
    for (int e = 0; e < 32; ++e) {
        int idx = e * 256 + tid;
        int sc = idx >> 4, tt = idx & 15;
        float v = skipbuf[sc * (NB * SKIP_LEN) + n * SKIP_LEN + tt0 + tt];
        ss[sc][tt] = fmaxf(v, 0.f);
    }
    __syncthreads();
    float accv[16];
    float bias = Eb[tid];
    #pragma unroll
    for (int i = 0; i < 16; ++i) accv[i] = bias;
    #pragma unroll 4
    for (int sc = 0; sc < 512; ++sc) {
        float wv = ET[sc * 256 + tid];
        #pragma unroll
        for (int i = 0; i < 16; ++i) accv[i] = fmaf(wv, ss[sc][i], accv[i]);
    }
    #pragma unroll
    for (int i = 0; i < 16; ++i)
        out[(n * SKIP_LEN + tt0 + i) * NCLS + tid] = accv[i];
}

extern "C" void kernel_launch(void* const* d_in, const int* in_sizes, int n_in,
                              void* d_out, int out_size, void* d_ws, size_t ws_size,
                              hipStream_t stream) {
    const float* input      = (const float*)d_in[0];
    const float* start_w    = (const float*)d_in[1];
    const float* dilated_w  = (const float*)d_in[2];
    const float* residual_w = (const float*)d_in[3];
    const float* skip_w     = (const float*)d_in[4];
    const float* end_w      = (const float*)d_in[5];
    const float* end_b      = (const float*)d_in[6];
    float* out = (float*)d_out;

    uint8_t* w8 = (uint8_t*)d_ws;
    uint16_t* Xh0   = (uint16_t*)(w8);
    uint16_t* Xl0   = (uint16_t*)(w8 + 4718592);
    uint16_t* Xh1   = (uint16_t*)(w8 + 9437184);
    uint16_t* Xl1   = (uint16_t*)(w8 + 14155776);
    float*    skipb = (float*)   (w8 + 18874368);
    uint16_t* AgH   = (uint16_t*)(w8 + 23068672);
    uint16_t* AgL   = (uint16_t*)(w8 + 28311552);
    uint16_t* WrH   = (uint16_t*)(w8 + 33554432);
    uint16_t* WrL   = (uint16_t*)(w8 + 34865152);
    uint16_t* WsH   = (uint16_t*)(w8 + 36175872);
    uint16_t* WsL   = (uint16_t*)(w8 + 41418752);
    float*    ET    = (float*)   (w8 + 46661632);

    hipMemsetAsync(skipb, 0, (size_t)512 * NB * SKIP_LEN * sizeof(float), stream);
    k_prep_a<<<dim3(320), 256, 0, stream>>>(dilated_w, AgH, AgL);
    k_prep_w<<<dim3(12800), 256, 0, stream>>>(residual_w, skip_w, WrH, WrL, WsH, WsL);
    k_prep_e<<<dim3(512), 256, 0, stream>>>(end_w, ET);
    k_start<<<dim3(2304, 4), 256, 0, stream>>>(input, start_w, Xh0, Xl0);

    for (int i = 0; i < NLAYER; ++i) {
        int d = 1 << (i % 10);
        const uint16_t* ih = (i & 1) ? Xh1 : Xh0;
        const uint16_t* il = (i & 1) ? Xl1 : Xl0;
        uint16_t* oh = (i & 1) ? Xh0 : Xh1;
        uint16_t* ol = (i & 1) ? Xl0 : Xl1;
        k_layer<<<dim3(144, 4), 256, 0, stream>>>(
            ih, il, oh, ol, skipb,
            AgH + (size_t)i * 65536, AgL + (size_t)i * 65536,
            WrH + (size_t)i * 16384, WrL + (size_t)i * 16384,
            WsH + (size_t)i * 65536, WsL + (size_t)i * 65536,
            d);
    }
    k_end<<<dim3(128), 256, 0, stream>>>(skipb, ET, end_b, out);
}

// Round 6
// 1302.016 us; speedup vs baseline: 3.2020x; 1.2708x over previous
//
#include <hip/hip_runtime.h>
#include <stdint.h>

#define NB 4
#define LSEQ 8192
#define TLOC 4608
#define TBASE 3584
#define NLAYER 40
#define SKIP_T0 4096
#define SKIP_LEN 512
#define NCLS 256

typedef float f32x4 __attribute__((ext_vector_type(4)));
typedef short bf16x8 __attribute__((ext_vector_type(8)));   // 8 bf16 in 4 VGPRs

typedef const __attribute__((address_space(1))) uint32_t GU32;
typedef __attribute__((address_space(3))) uint32_t LU32;

__device__ __forceinline__ void gload16(const void* g, void* l) {
    __builtin_amdgcn_global_load_lds((GU32*)g, (LU32*)l, 16, 0, 0);
}

__device__ __forceinline__ uint16_t f2bf(float x) {
    uint32_t u = __builtin_bit_cast(uint32_t, x);
    uint32_t r = (u + 0x7FFFu + ((u >> 16) & 1u)) >> 16;   // RNE
    return (uint16_t)r;
}
__device__ __forceinline__ float bf2f(uint16_t h) {
    uint32_t u = ((uint32_t)h) << 16;
    return __builtin_bit_cast(float, u);
}
__device__ __forceinline__ uint2 pack4(const uint16_t a[4]) {
    return make_uint2((uint32_t)a[0] | ((uint32_t)a[1] << 16),
                      (uint32_t)a[2] | ((uint32_t)a[3] << 16));
}

// ---------------- prep: dilated weights -> pre-swizzled split-bf16 global image ----------
// image per layer: 8 chunks x [co 256][kkc 32] u16, in-row u16 index = kkc ^ (((co>>1)&3)<<3)
// value at (co, kk=ch*32+kkc) = Wd[i][co][ci][kt], kk = kt*128+ci
__global__ __launch_bounds__(256) void k_prep_a(const float* __restrict__ Wd,
                                                uint16_t* __restrict__ AgH,
                                                uint16_t* __restrict__ AgL) {
    __shared__ float tile[32][257];
    int bi = blockIdx.x;
    int i = bi >> 3;
    int co0 = (bi & 7) * 32;
    int tid = threadIdx.x;
    #pragma unroll
    for (int e = 0; e < 32; ++e) {
        int idx = e * 256 + tid;
        int co_l = idx >> 8, rem = idx & 255;
        tile[co_l][rem] = Wd[(size_t)(i * 256 + co0 + co_l) * 256 + rem];
    }
    __syncthreads();
    #pragma unroll
    for (int e = 0; e < 32; ++e) {
        int co_l = e;
        int kk = tid;
        int ci = kk & 127, kt = kk >> 7;
        float v = tile[co_l][ci * 2 + kt];
        uint16_t h = f2bf(v);
        uint16_t lo = f2bf(v - bf2f(h));
        int co = co0 + co_l;
        int ch = kk >> 5, kkc = kk & 31;
        size_t o = ((size_t)(i * 8 + ch) * 256 + co) * 32 + (kkc ^ (((co >> 1) & 3) << 3));
        AgH[o] = h;
        AgL[o] = lo;
    }
}

// ---------------- prep: residual & skip weights -> straight split bf16 (x4 vectorized) ----------
__global__ __launch_bounds__(256) void k_prep_w(const float* __restrict__ Wr, const float* __restrict__ Ws,
                                                uint16_t* __restrict__ WrH, uint16_t* __restrict__ WrL,
                                                uint16_t* __restrict__ WsH, uint16_t* __restrict__ WsL) {
    int idx4 = (blockIdx.x * 256 + threadIdx.x) * 4;
    const int NR = NLAYER * 16384;
    const float* src = (idx4 < NR) ? (Wr + idx4) : (Ws + (idx4 - NR));
    uint16_t* dH = (idx4 < NR) ? (WrH + idx4) : (WsH + (idx4 - NR));
    uint16_t* dL = (idx4 < NR) ? (WrL + idx4) : (WsL + (idx4 - NR));
    float4 v = *(const float4*)src;
    uint16_t h[4], lo[4];
    float vv[4] = {v.x, v.y, v.z, v.w};
    #pragma unroll
    for (int r = 0; r < 4; ++r) {
        h[r] = f2bf(vv[r]);
        lo[r] = f2bf(vv[r] - bf2f(h[r]));
    }
    *(uint2*)dH = pack4(h);
    *(uint2*)dL = pack4(lo);
}

// ---------------- prep: ET[sc][cl] = Ew[cl][sc] ----------
__global__ __launch_bounds__(256) void k_prep_e(const float* __restrict__ Ew,
                                                float* __restrict__ ET) {
    int idx = blockIdx.x * 256 + threadIdx.x;
    int cl = idx & 255;
    int sc = idx >> 8;
    ET[sc * 256 + cl] = Ew[cl * 512 + sc];
}

// ---------------- start conv: X[n][t][c] = sw[c]*input, split hi/lo ----------
__global__ __launch_bounds__(256) void k_start(const float* __restrict__ input,
                                               const float* __restrict__ sw,
                                               uint16_t* __restrict__ Xh, uint16_t* __restrict__ Xl) {
    int n = blockIdx.y;
    int inner = blockIdx.x * 256 + threadIdx.x;     // over 4608*128
    int t = inner >> 7, c = inner & 127;
    float x = sw[c] * input[n * LSEQ + TBASE + t];
    uint16_t h = f2bf(x);
    size_t o = (size_t)(n * TLOC + t) * 128 + c;
    Xh[o] = h;
    Xl[o] = f2bf(x - bf2f(h));
}

// ---------------- one WaveNet layer: dbuf-pipelined MFMA conv + gate + residual + fused skip ----------
__global__ __launch_bounds__(256, 2) void k_layer(
    const uint16_t* __restrict__ XhIn, const uint16_t* __restrict__ XlIn,
    uint16_t* __restrict__ XhOut, uint16_t* __restrict__ XlOut,
    float* __restrict__ skipbuf,
    const uint16_t* __restrict__ AgH, const uint16_t* __restrict__ AgL,  // layer slab, pre-swizzled
    const uint16_t* __restrict__ WrH, const uint16_t* __restrict__ WrL,  // [128][128]
    const uint16_t* __restrict__ WsH, const uint16_t* __restrict__ WsL,  // [512][128]
    int d)
{
    __shared__ uint16_t As[2][16384];   // [buf][ H 8192 | L 8192 ]  (64 KB)
    __shared__ uint16_t Bs[2][2048];    // [buf][ H 1024 | L 1024 ]  (8 KB)

    const int tid = threadIdx.x;
    const int w  = tid >> 6;
    const int l  = tid & 63;
    const int g  = l >> 4;
    const int lq = l & 15;
    const int tb = 143 - blockIdx.x;    // skip-heavy tiles (tb>=128) dispatched first
    const int t0 = tb * 32;
    const int nb = blockIdx.y;

    f32x4 acc[2][2][2];   // [pm][mi][ni]
    #pragma unroll
    for (int pm = 0; pm < 2; ++pm)
        #pragma unroll
        for (int mi = 0; mi < 2; ++mi)
            #pragma unroll
            for (int ni = 0; ni < 2; ++ni)
                acc[pm][mi][ni] = (f32x4){0.f, 0.f, 0.f, 0.f};

#define STAGE(ch, buf) do {                                                             \
    _Pragma("unroll")                                                                   \
    for (int j = 0; j < 4; ++j) {                                                       \
        gload16(AgH + (size_t)(ch) * 8192 + (j * 256 + tid) * 8,                        \
                &As[buf][(j * 256 + tid) * 8]);                                         \
        gload16(AgL + (size_t)(ch) * 8192 + (j * 256 + tid) * 8,                        \
                &As[buf][8192 + (j * 256 + tid) * 8]);                                  \
    }                                                                                   \
    {   int s = tid & 127;                                                              \
        int b = s * 16;                                                                 \
        int tt = b >> 6;                                                                \
        int e = (b & 63) ^ (((tt >> 1) & 3) << 4);                                      \
        int ci = (((ch) & 3) << 5) + (e >> 1);                                          \
        int t = t0 + tt - (((ch) < 4) ? d : 0);                                         \
        if (t < 0) t = 0;                                                               \
        size_t gi = (size_t)(nb * TLOC + t) * 128 + ci;                                 \
        if (tid < 128) gload16(XhIn + gi, &Bs[buf][s * 8]);                             \
        else           gload16(XlIn + gi, &Bs[buf][1024 + s * 8]);                      \
    } } while (0)

    // ---- main GEMM: h[co 256][tt 32] = sum_kk A[kk][co]*B[kk][tt], 8 chunks, dbuf pipeline ----
    STAGE(0, 0);
    #pragma unroll
    for (int ch = 0; ch < 8; ++ch) {
        __syncthreads();                       // drains vmcnt: STAGE(ch) landed; prev compute done
        if (ch < 7) STAGE(ch + 1, (ch + 1) & 1);
        const uint16_t* AsH = &As[ch & 1][0];
        const uint16_t* AsL = &As[ch & 1][8192];
        const uint16_t* BsH = &Bs[ch & 1][0];
        const uint16_t* BsL = &Bs[ch & 1][1024];

        bf16x8 Bh[2], Bl[2];
        #pragma unroll
        for (int ni = 0; ni < 2; ++ni) {
            int tt = ni * 16 + lq;
            int byte = (tt * 64 + g * 16) ^ (((tt >> 1) & 3) << 4);
            Bh[ni] = *(const bf16x8*)((const char*)BsH + byte);
            Bl[ni] = *(const bf16x8*)((const char*)BsL + byte);
        }
        bf16x8 Ah[2][2], Al[2][2];
        #pragma unroll
        for (int pm = 0; pm < 2; ++pm)
            #pragma unroll
            for (int mi = 0; mi < 2; ++mi) {
                int co = pm * 128 + w * 32 + mi * 16 + lq;
                int byte = (co * 64 + g * 16) ^ (((co >> 1) & 3) << 4);
                Ah[pm][mi] = *(const bf16x8*)((const char*)AsH + byte);
                Al[pm][mi] = *(const bf16x8*)((const char*)AsL + byte);
            }
        #pragma unroll
        for (int pm = 0; pm < 2; ++pm)
            #pragma unroll
            for (int mi = 0; mi < 2; ++mi)
                #pragma unroll
                for (int ni = 0; ni < 2; ++ni) {
                    f32x4 c = acc[pm][mi][ni];
                    c = __builtin_amdgcn_mfma_f32_16x16x32_bf16(Ah[pm][mi], Bh[ni], c, 0, 0, 0);
                    c = __builtin_amdgcn_mfma_f32_16x16x32_bf16(Ah[pm][mi], Bl[ni], c, 0, 0, 0);
                    c = __builtin_amdgcn_mfma_f32_16x16x32_bf16(Al[pm][mi], Bh[ni], c, 0, 0, 0);
                    acc[pm][mi][ni] = c;
                }
    }
#undef STAGE

    // ---- Wr register prefetch (consumed after gate barrier; latency hidden) ----
    bf16x8 wrh[2][4], wrl[2][4];
    #pragma unroll
    for (int mi = 0; mi < 2; ++mi) {
        int rc = w * 32 + mi * 16 + lq;
        #pragma unroll
        for (int c4 = 0; c4 < 4; ++c4) {
            int dc0 = c4 * 32 + g * 8;
            wrh[mi][c4] = *(const bf16x8*)(WrH + rc * 128 + dc0);
            wrl[mi][c4] = *(const bf16x8*)(WrL + rc * 128 + dc0);
        }
    }

    // ---- gate (intra-thread pairing co / co+128) -> Zt in LDS (overlays As[0], dead now) ----
    uint16_t* ZtH = &As[0][0];
    uint16_t* ZtL = &As[0][4096];
    #pragma unroll
    for (int mi = 0; mi < 2; ++mi)
        #pragma unroll
        for (int ni = 0; ni < 2; ++ni) {
            uint16_t zh[4], zl[4];
            #pragma unroll
            for (int r = 0; r < 4; ++r) {
                float h1 = acc[0][mi][ni][r];
                float h2 = acc[1][mi][ni][r];
                float e1 = __builtin_amdgcn_exp2f(h1 * -2.885390082f);   // e^{-2 h1}
                float th = 2.0f * __builtin_amdgcn_rcpf(1.0f + e1) - 1.0f;
                float e2 = __builtin_amdgcn_exp2f(h2 * -1.442695041f);   // e^{-h2}
                float sg = __builtin_amdgcn_rcpf(1.0f + e2);
                float z = th * sg;
                zh[r] = f2bf(z);
                zl[r] = f2bf(z - bf2f(zh[r]));
            }
            int tt = ni * 16 + lq;
            int dc0 = w * 32 + mi * 16 + g * 4;
            int idx = tt * 128 + (dc0 ^ ((tt & 7) << 3));
            *(uint2*)(ZtH + idx) = pack4(zh);
            *(uint2*)(ZtL + idx) = pack4(zl);
        }
    __syncthreads();

    // ---- residual GEMM: r[rc 128][tt 32] = Wr * z (weights in regs) ----
    f32x4 racc[2][2];
    #pragma unroll
    for (int mi = 0; mi < 2; ++mi)
        #pragma unroll
        for (int ni = 0; ni < 2; ++ni)
            racc[mi][ni] = (f32x4){0.f, 0.f, 0.f, 0.f};
    #pragma unroll
    for (int c4 = 0; c4 < 4; ++c4) {
        int dc0 = c4 * 32 + g * 8;
        bf16x8 bh[2], bl[2];
        #pragma unroll
        for (int ni = 0; ni < 2; ++ni) {
            int tt = ni * 16 + lq;
            int idx = tt * 128 + (dc0 ^ ((tt & 7) << 3));
            bh[ni] = *(const bf16x8*)(ZtH + idx);
            bl[ni] = *(const bf16x8*)(ZtL + idx);
        }
        #pragma unroll
        for (int mi = 0; mi < 2; ++mi)
            #pragma unroll
            for (int ni = 0; ni < 2; ++ni) {
                f32x4 c = racc[mi][ni];
                c = __builtin_amdgcn_mfma_f32_16x16x32_bf16(wrh[mi][c4], bh[ni], c, 0, 0, 0);
                c = __builtin_amdgcn_mfma_f32_16x16x32_bf16(wrh[mi][c4], bl[ni], c, 0, 0, 0);
                c = __builtin_amdgcn_mfma_f32_16x16x32_bf16(wrl[mi][c4], bh[ni], c, 0, 0, 0);
                racc[mi][ni] = c;
            }
    }
    // residual epilogue: Xout = racc + Xin (b64 hi/lo I/O)
    #pragma unroll
    for (int mi = 0; mi < 2; ++mi)
        #pragma unroll
        for (int ni = 0; ni < 2; ++ni) {
            int tt = ni * 16 + lq;
            int c0 = w * 32 + mi * 16 + g * 4;
            size_t gi = (size_t)(nb * TLOC + t0 + tt) * 128 + c0;
            uint2 xh = *(const uint2*)(XhIn + gi);
            uint2 xl = *(const uint2*)(XlIn + gi);
            uint16_t oh[4], ol[4];
            #pragma unroll
            for (int r = 0; r < 4; ++r) {
                uint16_t hh = (uint16_t)(((r < 2 ? xh.x : xh.y) >> ((r & 1) * 16)) & 0xFFFF);
                uint16_t ll = (uint16_t)(((r < 2 ? xl.x : xl.y) >> ((r & 1) * 16)) & 0xFFFF);
                float x = bf2f(hh) + bf2f(ll) + racc[mi][ni][r];
                oh[r] = f2bf(x);
                ol[r] = f2bf(x - bf2f(oh[r]));
            }
            *(uint2*)(XhOut + gi) = pack4(oh);
            *(uint2*)(XlOut + gi) = pack4(ol);
        }

    // ---- fused skip conv for output-window tiles: skip[sc 512][tt 32] += Ws * z ----
    if (t0 >= SKIP_T0) {
        #pragma unroll
        for (int hf = 0; hf < 2; ++hf) {
            f32x4 sacc[4][2];
            #pragma unroll
            for (int mi = 0; mi < 4; ++mi)
                #pragma unroll
                for (int ni = 0; ni < 2; ++ni)
                    sacc[mi][ni] = (f32x4){0.f, 0.f, 0.f, 0.f};
            #pragma unroll
            for (int c4 = 0; c4 < 4; ++c4) {
                int dc0 = c4 * 32 + g * 8;
                bf16x8 bh[2], bl[2];
                #pragma unroll
                for (int ni = 0; ni < 2; ++ni) {
                    int tt = ni * 16 + lq;
                    int idx = tt * 128 + (dc0 ^ ((tt & 7) << 3));
                    bh[ni] = *(const bf16x8*)(ZtH + idx);
                    bl[ni] = *(const bf16x8*)(ZtL + idx);
                }
                #pragma unroll
                for (int mi = 0; mi < 4; ++mi) {
                    int sc = hf * 256 + w * 64 + mi * 16 + lq;
                    bf16x8 ah = *(const bf16x8*)(WsH + sc * 128 + dc0);
                    bf16x8 al = *(const bf16x8*)(WsL + sc * 128 + dc0);
                    #pragma unroll
                    for (int ni = 0; ni < 2; ++ni) {
                        f32x4 c = sacc[mi][ni];
                        c = __builtin_amdgcn_mfma_f32_16x16x32_bf16(ah, bh[ni], c, 0, 0, 0);
                        c = __builtin_amdgcn_mfma_f32_16x16x32_bf16(ah, bl[ni], c, 0, 0, 0);
                        c = __builtin_amdgcn_mfma_f32_16x16x32_bf16(al, bh[ni], c, 0, 0, 0);
                        sacc[mi][ni] = c;
                    }
                }
            }
            #pragma unroll
            for (int mi = 0; mi < 4; ++mi)
                #pragma unroll
                for (int ni = 0; ni < 2; ++ni)
                    #pragma unroll
                    for (int r = 0; r < 4; ++r) {
                        int sc = hf * 256 + w * 64 + mi * 16 + g * 4 + r;
                        int ts = t0 - SKIP_T0 + ni * 16 + lq;
                        skipbuf[sc * (NB * SKIP_LEN) + nb * SKIP_LEN + ts] += sacc[mi][ni][r];
                    }
        }
    }
}

// ---------------- end conv stage 1: partial over 128-sc quarter ----------
__global__ __launch_bounds__(256) void k_end1(const float* __restrict__ skipbuf,
                                              const float* __restrict__ ET,
                                              float* __restrict__ partial) {
    __shared__ float ss[128][17];
    int bx = blockIdx.x;           // 0..511
    int scq = bx >> 7;
    int n = (bx >> 5) & 3;
    int tt0 = (bx & 31) * 16;
    int tid = threadIdx.x;
    #pragma unroll
    for (int e = 0; e < 8; ++e) {
        int idx = e * 256 + tid;
        int sc_l = idx >> 4, tt = idx & 15;
        float v = skipbuf[(scq * 128 + sc_l) * (NB * SKIP_LEN) + n * SKIP_LEN + tt0 + tt];
        ss[sc_l][tt] = fmaxf(v, 0.f);
    }
    __syncthreads();
    float accv[16];
    #pragma unroll
    for (int i = 0; i < 16; ++i) accv[i] = 0.f;
    #pragma unroll 4
    for (int sc_l = 0; sc_l < 128; ++sc_l) {
        float wv = ET[(scq * 128 + sc_l) * 256 + tid];
        #pragma unroll
        for (int i = 0; i < 16; ++i) accv[i] = fmaf(wv, ss[sc_l][i], accv[i]);
    }
    #pragma unroll
    for (int i = 0; i < 16; ++i)
        partial[((size_t)scq * 2048 + n * 512 + tt0 + i) * 256 + tid] = accv[i];
}

// ---------------- end conv stage 2: reduce 4 partials + bias ----------
__global__ __launch_bounds__(256) void k_end2(const float* __restrict__ partial,
                                              const float* __restrict__ Eb,
                                              float* __restrict__ out) {
    int o = blockIdx.x * 256 + threadIdx.x;   // 0..524287
    float v = Eb[threadIdx.x];
    #pragma unroll
    for (int q = 0; q < 4; ++q) v += partial[(size_t)q * 524288 + o];
    out[o] = v;
}

extern "C" void kernel_launch(void* const* d_in, const int* in_sizes, int n_in,
                              void* d_out, int out_size, void* d_ws, size_t ws_size,
                              hipStream_t stream) {
    const float* input      = (const float*)d_in[0];
    const float* start_w    = (const float*)d_in[1];
    const float* dilated_w  = (const float*)d_in[2];
    const float* residual_w = (const float*)d_in[3];
    const float* skip_w     = (const float*)d_in[4];
    const float* end_w      = (const float*)d_in[5];
    const float* end_b      = (const float*)d_in[6];
    float* out = (float*)d_out;

    uint8_t* w8 = (uint8_t*)d_ws;
    uint16_t* Xh0   = (uint16_t*)(w8);
    uint16_t* Xl0   = (uint16_t*)(w8 + 4718592);
    uint16_t* Xh1   = (uint16_t*)(w8 + 9437184);
    uint16_t* Xl1   = (uint16_t*)(w8 + 14155776);
    float*    skipb = (float*)   (w8 + 18874368);
    uint16_t* AgH   = (uint16_t*)(w8 + 23068672);
    uint16_t* AgL   = (uint16_t*)(w8 + 28311552);
    uint16_t* WrH   = (uint16_t*)(w8 + 33554432);
    uint16_t* WrL   = (uint16_t*)(w8 + 34865152);
    uint16_t* WsH   = (uint16_t*)(w8 + 36175872);
    uint16_t* WsL   = (uint16_t*)(w8 + 41418752);
    float*    ET    = (float*)   (w8 + 46661632);
    float*    partial = (float*)w8;   // overlays Xh0/Xl0 (dead after layer 39)

    hipMemsetAsync(skipb, 0, (size_t)512 * NB * SKIP_LEN * sizeof(float), stream);
    k_prep_a<<<dim3(320), 256, 0, stream>>>(dilated_w, AgH, AgL);
    k_prep_w<<<dim3(3200), 256, 0, stream>>>(residual_w, skip_w, WrH, WrL, WsH, WsL);
    k_prep_e<<<dim3(512), 256, 0, stream>>>(end_w, ET);
    k_start<<<dim3(2304, 4), 256, 0, stream>>>(input, start_w, Xh0, Xl0);

    for (int i = 0; i < NLAYER; ++i) {
        int d = 1 << (i % 10);
        const uint16_t* ih = (i & 1) ? Xh1 : Xh0;
        const uint16_t* il = (i & 1) ? Xl1 : Xl0;
        uint16_t* oh = (i & 1) ? Xh0 : Xh1;
        uint16_t* ol = (i & 1) ? Xl0 : Xl1;
        k_layer<<<dim3(144, 4), 256, 0, stream>>>(
            ih, il, oh, ol, skipb,
            AgH + (size_t)i * 65536, AgL + (size_t)i * 65536,
            WrH + (size_t)i * 16384, WrL + (size_t)i * 16384,
            WsH + (size_t)i * 65536, WsL + (size_t)i * 65536,
            d);
    }
    k_end1<<<dim3(512), 256, 0, stream>>>(skipb, ET, partial);
    k_end2<<<dim3(2048), 256, 0, stream>>>(partial, end_b, out);
}